// Round 7
// baseline (1669.349 us; speedup 1.0000x reference)
//
#include <hip/hip_runtime.h>

// CobaLIF SNN forward. B=256, T=1000, F=700, H=256, O=20.
// drive_k: one wave per (b,t). Active-feature list in wave-private LDS via
//   ballot+mbcnt; 8 independent fp8 uint2 gathers per iter; cvt_pk_f32_fp8
//   unpack. (Unchanged from round 6 for attribution.)
// drive0_k: exact fp32 drive for t=0 (the only marginal-threshold step).
// snn_main_k (REWRITTEN): 4 waves per block = one per SIMD, ONE h per lane
//   (h = 64*wave + lane). Per step: ballot -> lane0 ds_write_b64 into a
//   double-buffered mask slot -> ONE __syncthreads -> all waves read the
//   256-bit non-fired mask. Recurrent/readout = precomputed totals minus
//   (normally empty) mask-driven corrections. Round 6 ran ONE wave per CU
//   (~960 cyc/step, 3 SIMDs idle); this gives 4-way issue overlap.

#define TT 1000
#define BB 256
#define FF 700
#define FP 704
#define HH 256
#define OO 20

typedef float v2f __attribute__((ext_vector_type(2)));

// ws layout (bytes):
#define WS_WBT   0          // u16 wbT[FP][HH]: (fp8 e4m3 relu(w_in), fp8 relu(-w_in)) bytes, [f][h]
#define WS_WRT   360448     // float2 wr2i[HH][HH]: row h' -> (relu(w_rec[h][h']), relu(-..)) per h
#define WS_RSUM  884736     // f32x2 rsum[HH] row sums of (w_rec_e, w_rec_i)
#define WS_WOT   886784     // f32 woT[HH][OO] w_out transposed
#define WS_CSUM  907264     // f32 csum[OO] column sums of w_out
#define WS_DRV0  907344     // f32x2 drv0[BB][HH] exact t=0 drive

__device__ __forceinline__ unsigned short f2bf(float x) {
    unsigned u = __float_as_uint(x);                    // x >= 0, finite
    return (unsigned short)((u + 0x7fffu + ((u >> 16) & 1u)) >> 16);  // RNE
}

__global__ __launch_bounds__(256) void prep_wbt_k(const float* __restrict__ w_in,
                                                  unsigned short* __restrict__ wbT) {
    int idx = blockIdx.x * 256 + threadIdx.x;           // idx = f*HH + h
    int f = idx >> 8, h = idx & 255;
    unsigned short val = 0;
    if (f < FF) {
        float w = w_in[h * FF + f];
        int pk = __builtin_amdgcn_cvt_pk_fp8_f32(fmaxf(w, 0.f), fmaxf(-w, 0.f), 0, false);
        val = (unsigned short)(pk & 0xffff);            // byte0 = e, byte1 = i
    }
    wbT[idx] = val;
}

__global__ __launch_bounds__(256) void prep_wr2_k(const float* __restrict__ w_rec,
                                                  float2* __restrict__ wr2i) {
    int idx = blockIdx.x * 256 + threadIdx.x;           // idx = h'*HH + h
    int hp = idx >> 8, h = idx & 255;
    float w = w_rec[h * HH + hp];                       // W[h][h']
    wr2i[idx] = make_float2(fmaxf(w, 0.f), fmaxf(-w, 0.f));
}

// blocks 0..255: rsum[h] + woT row h. block 256: csum.
__global__ __launch_bounds__(64) void prep_red_k(const float* __restrict__ w_rec,
                                                 const float* __restrict__ w_out,
                                                 float2* __restrict__ rsum,
                                                 float* __restrict__ woT,
                                                 float* __restrict__ csum) {
    const int blk = blockIdx.x, l = threadIdx.x;
    if (blk < HH) {
        const int h = blk;
        float se = 0.f, si = 0.f;
        #pragma unroll
        for (int c = 0; c < 4; ++c) {
            float w = w_rec[h * HH + c * 64 + l];
            se += fmaxf(w, 0.f);
            si += fmaxf(-w, 0.f);
        }
        #pragma unroll
        for (int m = 32; m; m >>= 1) {
            se += __shfl_xor(se, m, 64);
            si += __shfl_xor(si, m, 64);
        }
        if (l == 0) rsum[h] = make_float2(se, si);
        if (l < OO) woT[h * OO + l] = w_out[l * HH + h];
    } else {
        for (int o = 0; o < OO; ++o) {
            float s = 0.f;
            #pragma unroll
            for (int c = 0; c < 4; ++c) s += w_out[o * HH + c * 64 + l];
            #pragma unroll
            for (int m = 32; m; m >>= 1) s += __shfl_xor(s, m, 64);
            if (l == 0) csum[o] = s;
        }
    }
}

// One wave per (b,t): ballot+mbcnt LDS list, VALU-only fp8 gather.
__global__ __launch_bounds__(256) void drive_k(const float* __restrict__ x,
                                               const unsigned short* __restrict__ wbT,
                                               uint4* __restrict__ drv4) {
    const int b = blockIdx.x;
    const int wv = threadIdx.x >> 6;
    const int t = blockIdx.y * 4 + wv;
    const int l = threadIdx.x & 63;
    __shared__ int lists[4][712];                 // wave-private; no barriers
    int* __restrict__ list = lists[wv];

    const float* xrow = x + ((size_t)b * TT + t) * FF;   // 2800 B, 16B-aligned
    float4 xq[3];
    #pragma unroll
    for (int r = 0; r < 3; ++r) {
        int q = r * 64 + l;                        // float4 index, 175 total
        if (q < 175) xq[r] = reinterpret_cast<const float4*>(xrow)[q];
        else         xq[r] = make_float4(0.f, 0.f, 0.f, 0.f);
    }
    // compact active features as BYTE OFFSETS (f*512) into LDS. f = r*256+4l+c.
    int n = 0;
    #pragma unroll
    for (int r = 0; r < 3; ++r) {
        float xa[4] = {xq[r].x, xq[r].y, xq[r].z, xq[r].w};
        #pragma unroll
        for (int c = 0; c < 4; ++c) {
            bool act = (xa[c] != 0.f);
            unsigned long long m = __ballot(act);
            int pre = __builtin_amdgcn_mbcnt_hi((unsigned)(m >> 32),
                      __builtin_amdgcn_mbcnt_lo((unsigned)m, 0));
            if (act) list[n + pre] = ((r << 8) + (l << 2) + c) << 9;
            n += __popcll(m);
        }
    }
    if (l < 8) list[n + l] = FF << 9;             // zero-row padding
    const int npad = (n + 7) & ~7;

    v2f a0 = {0.f, 0.f}, a1 = {0.f, 0.f}, a2 = {0.f, 0.f}, a3 = {0.f, 0.f};
    const char* bp = (const char*)wbT + (size_t)(l * 8);
    for (int k = 0; k < npad; k += 8) {
        int4 oA = *(const int4*)&list[k];          // uniform-addr b128 broadcast
        int4 oB = *(const int4*)&list[k + 4];
        uint2 u0 = *(const uint2*)(bp + oA.x);
        uint2 u1 = *(const uint2*)(bp + oA.y);
        uint2 u2 = *(const uint2*)(bp + oA.z);
        uint2 u3 = *(const uint2*)(bp + oA.w);
        uint2 u4 = *(const uint2*)(bp + oB.x);
        uint2 u5 = *(const uint2*)(bp + oB.y);
        uint2 u6 = *(const uint2*)(bp + oB.z);
        uint2 u7 = *(const uint2*)(bp + oB.w);
        #define ACC(u) \
            a0 += __builtin_amdgcn_cvt_pk_f32_fp8((int)(u).x, false); \
            a1 += __builtin_amdgcn_cvt_pk_f32_fp8((int)(u).x, true);  \
            a2 += __builtin_amdgcn_cvt_pk_f32_fp8((int)(u).y, false); \
            a3 += __builtin_amdgcn_cvt_pk_f32_fp8((int)(u).y, true);
        ACC(u0) ACC(u1) ACC(u2) ACC(u3) ACC(u4) ACC(u5) ACC(u6) ACC(u7)
        #undef ACC
    }
    uint4 o;
    o.x = (unsigned)f2bf(a0.x) | ((unsigned)f2bf(a0.y) << 16);
    o.y = (unsigned)f2bf(a1.x) | ((unsigned)f2bf(a1.y) << 16);
    o.z = (unsigned)f2bf(a2.x) | ((unsigned)f2bf(a2.y) << 16);
    o.w = (unsigned)f2bf(a3.x) | ((unsigned)f2bf(a3.y) << 16);
    drv4[((size_t)t * BB + b) * 64 + l] = o;
}

// Ballot-based active-feature compaction (256-thread blocks), for drive0 only.
__device__ __forceinline__ int build_list(const float* __restrict__ xrow,
                                          int tid, int* __restrict__ xact,
                                          int* __restrict__ wcnt) {
    int lane = tid & 63, w = tid >> 6;
    float4 xv = make_float4(0.f, 0.f, 0.f, 0.f);
    if (tid < 175) xv = reinterpret_cast<const float4*>(xrow)[tid];
    unsigned long long b0 = __ballot(xv.x != 0.f);
    unsigned long long b1 = __ballot(xv.y != 0.f);
    unsigned long long b2 = __ballot(xv.z != 0.f);
    unsigned long long b3 = __ballot(xv.w != 0.f);
    int c0 = __popcll(b0), c1 = __popcll(b1), c2 = __popcll(b2), c3 = __popcll(b3);
    if (lane == 0) wcnt[w] = c0 + c1 + c2 + c3;
    __syncthreads();
    int base = 0;
    for (int i = 0; i < w; ++i) base += wcnt[i];
    int ntot = wcnt[0] + wcnt[1] + wcnt[2] + wcnt[3];
    unsigned long long below = (1ull << lane) - 1ull;
    if (xv.x != 0.f) xact[base + __popcll(b0 & below)] = 4 * tid + 0;
    if (xv.y != 0.f) xact[base + c0 + __popcll(b1 & below)] = 4 * tid + 1;
    if (xv.z != 0.f) xact[base + c0 + c1 + __popcll(b2 & below)] = 4 * tid + 2;
    if (xv.w != 0.f) xact[base + c0 + c1 + c2 + __popcll(b3 & below)] = 4 * tid + 3;
    int npad = (ntot + 7) & ~7;
    if (tid < npad - ntot) xact[ntot + tid] = FF;        // dummy (guarded out)
    __syncthreads();
    return npad;
}

// Exact fp32 drive for t=0 only.
__global__ __launch_bounds__(256) void drive0_k(const float* __restrict__ x,
                                                const float* __restrict__ w_in,
                                                float2* __restrict__ drv0) {
    const int b = blockIdx.x, tid = threadIdx.x;
    __shared__ int xact[712];
    __shared__ int wcnt[4];
    int npad = build_list(x + (size_t)b * TT * FF, tid, xact, wcnt);
    float ie = 0.f, ii = 0.f;
    for (int k = 0; k < npad; ++k) {
        int f = __builtin_amdgcn_readfirstlane(xact[k]);
        float w = (f < FF) ? w_in[tid * FF + f] : 0.f;
        ie += fmaxf(w, 0.f);
        ii += fmaxf(-w, 0.f);
    }
    drv0[b * HH + tid] = make_float2(ie, ii);
}

__global__ __launch_bounds__(256) void snn_main_k(
    const float2* __restrict__ drv0, const float2* __restrict__ wr2i,
    const float2* __restrict__ rsum, const float* __restrict__ woT,
    const float* __restrict__ csum, float* __restrict__ out) {
    const int b = blockIdx.x, tid = threadIdx.x;
    const int w = tid >> 6, l = tid & 63;
    const int h = tid;                                   // wave w owns h=64w..64w+63

    __shared__ unsigned long long mbuf[2][4];            // double-buffered nf masks

    float* __restrict__ volt = out;                          // [T,B,O]
    float* __restrict__ spk  = out + (size_t)TT * BB * OO;   // [T,B,H]
    const unsigned* __restrict__ drv = (const unsigned*)spk; // aliases spikes

    const float2 rs = rsum[h];
    const float cs = (tid < OO) ? csum[tid] : 0.f;
    float ge, gi, v = 0.f, vo = 0.f, io = 0.f;

    #define RING 16
    unsigned dring[RING];                                // slot (t-1)&15 holds step t
    #pragma unroll
    for (int j = 0; j < RING; ++j)
        dring[j] = drv[((size_t)(1 + j) * BB + b) * HH + h];

    unsigned long long mp0, mp1, mp2, mp3;               // prev-step non-fired

    // ---- t = 0: exact fp32 drive, z_prev = 0 ----
    {
        float2 d0 = drv0[(size_t)b * HH + h];
        ge = d0.x; gi = d0.y;
        v = 0.5f * ge * 60.f;                            // from v=0, E_REV_I=V_REST=0
        float z = (v - 1.f > 0.f) ? 1.f : 0.f;
        v *= (1.f - z);
        spk[((size_t)0 * BB + b) * HH + h] = z;
        unsigned long long nf = __ballot(z == 0.f);
        if (l == 0) mbuf[0][w] = nf;
        __syncthreads();
        mp0 = mbuf[0][0]; mp1 = mbuf[0][1]; mp2 = mbuf[0][2]; mp3 = mbuf[0][3];
        if (tid < OO) {
            float corr = 0.f;
            unsigned long long mm;
            mm = mp0; while (mm) { int i = __ffsll(mm) - 1; mm &= mm - 1; corr += woT[(0*64+i)*OO + tid]; }
            mm = mp1; while (mm) { int i = __ffsll(mm) - 1; mm &= mm - 1; corr += woT[(1*64+i)*OO + tid]; }
            mm = mp2; while (mm) { int i = __ffsll(mm) - 1; mm &= mm - 1; corr += woT[(2*64+i)*OO + tid]; }
            mm = mp3; while (mm) { int i = __ffsll(mm) - 1; mm &= mm - 1; corr += woT[(3*64+i)*OO + tid]; }
            vo = vo + 0.01f * (io - vo);                 // old io (reference order)
            io = 0.98f * io + (cs - corr);
            volt[((size_t)0 * BB + b) * OO + tid] = vo;
        }
    }

    // ---- t = 1 .. 999 ----
    for (int t = 1; t < TT; ++t) {
        const int slot = (t - 1) & (RING - 1);
        const unsigned cu = dring[slot];
        int tn = t + RING; if (tn > TT - 1) tn = TT - 1;
        dring[slot] = drv[((size_t)tn * BB + b) * HH + h];

        float ie = __uint_as_float(cu << 16);
        float ii = __uint_as_float(cu & 0xffff0000u);
        float ce = 0.f, ci = 0.f;
        if (mp0 | mp1 | mp2 | mp3) {
            unsigned long long mm;
            #pragma unroll
            for (int q = 0; q < 4; ++q) {
                mm = (q == 0) ? mp0 : (q == 1) ? mp1 : (q == 2) ? mp2 : mp3;
                while (mm) {
                    int i = __ffsll(mm) - 1; mm &= mm - 1;
                    float2 wv = wr2i[(size_t)(q * 64 + i) * HH + h];
                    ce += wv.x; ci += wv.y;
                }
            }
        }
        ge = 0.98f * ge + ie + (rs.x - ce);
        gi = 0.99f * gi + ii + (rs.y - ci);
        v = v + 0.5f * (0.25f * (0.f - v) + ge * (60.f - v) + gi * (0.f - v));
        float z = (v - 1.f > 0.f) ? 1.f : 0.f;
        v *= (1.f - z);
        spk[((size_t)t * BB + b) * HH + h] = z;

        unsigned long long nf = __ballot(z == 0.f);
        if (l == 0) mbuf[t & 1][w] = nf;
        __syncthreads();
        mp0 = mbuf[t & 1][0]; mp1 = mbuf[t & 1][1];
        mp2 = mbuf[t & 1][2]; mp3 = mbuf[t & 1][3];

        if (tid < OO) {
            float corr = 0.f;
            if (mp0 | mp1 | mp2 | mp3) {
                unsigned long long mm;
                mm = mp0; while (mm) { int i = __ffsll(mm) - 1; mm &= mm - 1; corr += woT[(0*64+i)*OO + tid]; }
                mm = mp1; while (mm) { int i = __ffsll(mm) - 1; mm &= mm - 1; corr += woT[(1*64+i)*OO + tid]; }
                mm = mp2; while (mm) { int i = __ffsll(mm) - 1; mm &= mm - 1; corr += woT[(2*64+i)*OO + tid]; }
                mm = mp3; while (mm) { int i = __ffsll(mm) - 1; mm &= mm - 1; corr += woT[(3*64+i)*OO + tid]; }
            }
            vo = vo + 0.01f * (io - vo);
            io = 0.98f * io + (cs - corr);
            volt[((size_t)t * BB + b) * OO + tid] = vo;
        }
    }
}

extern "C" void kernel_launch(void* const* d_in, const int* in_sizes, int n_in,
                              void* d_out, int out_size, void* d_ws, size_t ws_size,
                              hipStream_t stream) {
    (void)in_sizes; (void)n_in; (void)out_size; (void)ws_size;
    const float* x     = (const float*)d_in[0];
    const float* w_in  = (const float*)d_in[1];
    const float* w_rec = (const float*)d_in[2];
    const float* w_out = (const float*)d_in[3];
    float* out = (float*)d_out;

    char* ws = (char*)d_ws;
    unsigned short* wbT = (unsigned short*)(ws + WS_WBT);
    float2*   wr2i = (float2*)  (ws + WS_WRT);
    float2*   rsum = (float2*)  (ws + WS_RSUM);
    float*    woT  = (float*)   (ws + WS_WOT);
    float*    csum = (float*)   (ws + WS_CSUM);
    float2*   drv0 = (float2*)  (ws + WS_DRV0);

    uint4* drv4 = (uint4*)(out + (size_t)TT * BB * OO);   // spike region

    hipLaunchKernelGGL(prep_wbt_k, dim3(FP * HH / 256), dim3(256), 0, stream, w_in, wbT);
    hipLaunchKernelGGL(prep_wr2_k, dim3(HH * HH / 256), dim3(256), 0, stream, w_rec, wr2i);
    hipLaunchKernelGGL(prep_red_k, dim3(HH + 1),        dim3(64),  0, stream,
                       w_rec, w_out, rsum, woT, csum);
    hipLaunchKernelGGL(drive0_k,   dim3(BB),            dim3(256), 0, stream, x, w_in, drv0);
    hipLaunchKernelGGL(drive_k,    dim3(BB, TT / 4),    dim3(256), 0, stream, x, wbT, drv4);
    hipLaunchKernelGGL(snn_main_k, dim3(BB),            dim3(256), 0, stream,
                       drv0, wr2i, rsum, woT, csum, out);
}

// Round 8
// 875.123 us; speedup vs baseline: 1.9076x; 1.9076x over previous
//
#include <hip/hip_runtime.h>

// CobaLIF SNN forward. B=256, T=1000, F=700, H=256, O=20.
//
// KEY THEOREM (verified by R1-R7 counters: correction masks always empty,
// absmax 0.0): for t>=1, if z(t-1)=all-ones then v(t) = 30*g_e(t) >=
// 30*rowsum(relu(w_rec)) ~ 270 >> 1, INDEPENDENT of the input drive (which
// only adds >=0). So z == 1 for all t>=1 by induction from z(0), and the
// readout input is constantly csum => voltages are batch-independent.
//   -> spikes: t=0 from exact fp32 drive; t>=1 pure 1.0 fill (262 MB).
//   -> voltages: one 1000-step scalar scan of 20 channels, broadcast to B.
// Exactness is NOT assumed: per-b flag (any z(0)==0) and global flag
// (min rowsum <= 0.04) gate fallback_k, a full sequential per-b recompute
// (R1/R6-proven structure). With this data all flags are 0.

#define TT 1000
#define BB 256
#define FF 700
#define HH 256
#define OO 20

// ws layout (bytes), total ~628 KB:
#define WS_WRT   0         // float2 wr2i[HH][HH]: [h'*HH+h] = (relu(W[h][h']), relu(-W[h][h']))
#define WS_RSUM  524288    // float2 rsum[HH]: row sums of (w_rec_e, w_rec_i)
#define WS_WOT   526336    // float woT[HH][OO]: w_out transposed
#define WS_CSUM  546816    // float csum[OO]: column sums of w_out
#define WS_VOC   546944    // float voc[TT][OO]: common voltage trace
#define WS_GFLAG 626944    // int: global fallback flag
#define WS_BFLAG 626948    // int[BB]: per-batch fallback flags

__global__ __launch_bounds__(256) void prep_wr2_k(const float* __restrict__ w_rec,
                                                  float2* __restrict__ wr2i) {
    int idx = blockIdx.x * 256 + threadIdx.x;           // idx = h'*HH + h
    int hp = idx >> 8, h = idx & 255;
    float w = w_rec[h * HH + hp];                       // W[h][h']
    wr2i[idx] = make_float2(fmaxf(w, 0.f), fmaxf(-w, 0.f));
}

// blocks 0..255: rsum[h] + woT row h. block 256: csum.
__global__ __launch_bounds__(64) void prep_red_k(const float* __restrict__ w_rec,
                                                 const float* __restrict__ w_out,
                                                 float2* __restrict__ rsum,
                                                 float* __restrict__ woT,
                                                 float* __restrict__ csum) {
    const int blk = blockIdx.x, l = threadIdx.x;
    if (blk < HH) {
        const int h = blk;
        float se = 0.f, si = 0.f;
        #pragma unroll
        for (int c = 0; c < 4; ++c) {
            float w = w_rec[h * HH + c * 64 + l];
            se += fmaxf(w, 0.f);
            si += fmaxf(-w, 0.f);
        }
        #pragma unroll
        for (int m = 32; m; m >>= 1) {
            se += __shfl_xor(se, m, 64);
            si += __shfl_xor(si, m, 64);
        }
        if (l == 0) rsum[h] = make_float2(se, si);
        if (l < OO) woT[h * OO + l] = w_out[l * HH + h];
    } else {
        for (int o = 0; o < OO; ++o) {
            float s = 0.f;
            #pragma unroll
            for (int c = 0; c < 4; ++c) s += w_out[o * HH + c * 64 + l];
            #pragma unroll
            for (int m = 32; m; m >>= 1) s += __shfl_xor(s, m, 64);
            if (l == 0) csum[o] = s;
        }
    }
}

// Ballot-based active-feature compaction (256-thread blocks).
__device__ __forceinline__ int build_list(const float* __restrict__ xrow,
                                          int tid, int* __restrict__ xact,
                                          int* __restrict__ wcnt) {
    int lane = tid & 63, w = tid >> 6;
    float4 xv = make_float4(0.f, 0.f, 0.f, 0.f);
    if (tid < 175) xv = reinterpret_cast<const float4*>(xrow)[tid];
    unsigned long long b0 = __ballot(xv.x != 0.f);
    unsigned long long b1 = __ballot(xv.y != 0.f);
    unsigned long long b2 = __ballot(xv.z != 0.f);
    unsigned long long b3 = __ballot(xv.w != 0.f);
    int c0 = __popcll(b0), c1 = __popcll(b1), c2 = __popcll(b2), c3 = __popcll(b3);
    if (lane == 0) wcnt[w] = c0 + c1 + c2 + c3;
    __syncthreads();
    int base = 0;
    for (int i = 0; i < w; ++i) base += wcnt[i];
    int ntot = wcnt[0] + wcnt[1] + wcnt[2] + wcnt[3];
    unsigned long long below = (1ull << lane) - 1ull;
    if (xv.x != 0.f) xact[base + __popcll(b0 & below)] = 4 * tid + 0;
    if (xv.y != 0.f) xact[base + c0 + __popcll(b1 & below)] = 4 * tid + 1;
    if (xv.z != 0.f) xact[base + c0 + c1 + __popcll(b2 & below)] = 4 * tid + 2;
    if (xv.w != 0.f) xact[base + c0 + c1 + c2 + __popcll(b3 & below)] = 4 * tid + 3;
    int npad = (ntot + 7) & ~7;
    if (tid < npad - ntot) xact[ntot + tid] = FF;        // padding (guarded out)
    __syncthreads();
    return npad;
}

// Exact fp32 t=0 drive -> spike row t=0 + per-b fallback flag.
__global__ __launch_bounds__(256) void drive0_k(const float* __restrict__ x,
                                                const float* __restrict__ w_in,
                                                float* __restrict__ spk0,
                                                int* __restrict__ bflag) {
    const int b = blockIdx.x, tid = threadIdx.x;
    __shared__ int xact[712];
    __shared__ int wcnt[4];
    __shared__ int nz;
    if (tid == 0) nz = 0;                    // visible after build_list's sync
    int npad = build_list(x + (size_t)b * TT * FF, tid, xact, wcnt);
    float ie = 0.f;
    for (int k = 0; k < npad; ++k) {
        int f = __builtin_amdgcn_readfirstlane(xact[k]);
        if (f < FF) {
            float w = w_in[tid * FF + f];
            ie += fmaxf(w, 0.f);
        }
    }
    float v0 = 0.5f * (ie * 60.f);           // reference association: DT*C_M_INV*(ge*(E-v))
    float z = (v0 - 1.f > 0.f) ? 1.f : 0.f;
    spk0[b * HH + tid] = z;
    if (z == 0.f) atomicAdd(&nz, 1);
    __syncthreads();
    if (tid == 0) bflag[b] = (nz != 0);
}

// Single block: global flag (induction premise) + common voltage scan.
__global__ __launch_bounds__(64) void volt_scan_k(const float2* __restrict__ rsum,
                                                  const float* __restrict__ csum,
                                                  float* __restrict__ voc,
                                                  int* __restrict__ gflag) {
    const int l = threadIdx.x;
    float mn = 1e30f;
    #pragma unroll
    for (int c = 0; c < 4; ++c) mn = fminf(mn, rsum[c * 64 + l].x);
    #pragma unroll
    for (int m = 32; m; m >>= 1) mn = fminf(mn, __shfl_xor(mn, m, 64));
    if (l == 0) gflag[0] = (mn <= 0.04f) ? 1 : 0;   // need rowsum_e > 1/30 w/ margin
    if (l < OO) {
        const float cs = csum[l];
        float vo = 0.f, io = 0.f;
        for (int t = 0; t < TT; ++t) {
            vo = vo + 0.01f * (io - vo);             // old io (reference order)
            io = 0.98f * io + cs;                    // i_in == csum (all-fire)
            voc[t * OO + l] = vo;
        }
    }
}

// Broadcast common voltage trace to all b. Block = t.
__global__ __launch_bounds__(256) void volt_fill_k(const float* __restrict__ voc,
                                                   float* __restrict__ volt) {
    const int t = blockIdx.x, b = threadIdx.x;
    float vv[20];
    #pragma unroll
    for (int o = 0; o < OO; ++o) vv[o] = voc[t * OO + o];   // thread-invariant
    float4* p = (float4*)(volt + ((size_t)t * BB + b) * OO);
    #pragma unroll
    for (int q = 0; q < 5; ++q)
        p[q] = make_float4(vv[4 * q], vv[4 * q + 1], vv[4 * q + 2], vv[4 * q + 3]);
}

// Fill spikes t>=1 with 1.0f. 262 MB coalesced stores.
__global__ __launch_bounds__(256) void spike_fill_k(float4* __restrict__ dst, long n4) {
    long i = (long)blockIdx.x * 256 + threadIdx.x;
    const long stride = (long)gridDim.x * 256;
    const float4 one = make_float4(1.f, 1.f, 1.f, 1.f);
    for (; i < n4; i += stride) dst[i] = one;
}

// Exact sequential recompute for flagged batches only (normally exits at once).
__global__ __launch_bounds__(256) void fallback_k(
    const float* __restrict__ x, const float* __restrict__ w_in,
    const float2* __restrict__ wr2i, const float2* __restrict__ rsum,
    const float* __restrict__ woT, const float* __restrict__ csum,
    const int* __restrict__ gflag, const int* __restrict__ bflag,
    float* __restrict__ out) {
    const int b = blockIdx.x, tid = threadIdx.x;
    if ((gflag[0] | bflag[b]) == 0) return;              // uniform early exit

    const int w = tid >> 6, l = tid & 63;
    __shared__ int xact[712];
    __shared__ int wcnt[4];
    __shared__ unsigned long long mbuf[4];

    float* __restrict__ volt = out;                          // [T,B,O]
    float* __restrict__ spk  = out + (size_t)TT * BB * OO;   // [T,B,H]

    const float2 rs = rsum[tid];
    const float cs = (tid < OO) ? csum[tid] : 0.f;
    float ge = 0.f, gi = 0.f, v = 0.f, vo = 0.f, io = 0.f;
    unsigned long long mp0 = 0, mp1 = 0, mp2 = 0, mp3 = 0;

    for (int t = 0; t < TT; ++t) {
        int npad = build_list(x + ((size_t)b * TT + t) * FF, tid, xact, wcnt);
        float ie = 0.f, ii = 0.f;
        for (int k = 0; k < npad; ++k) {
            int f = __builtin_amdgcn_readfirstlane(xact[k]);
            if (f < FF) {
                float wv = w_in[tid * FF + f];
                ie += fmaxf(wv, 0.f);
                ii += fmaxf(-wv, 0.f);
            }
        }
        float ce, ci;
        if (t == 0) { ce = rs.x; ci = rs.y; }            // z_prev = 0 exactly
        else {
            ce = 0.f; ci = 0.f;
            if (mp0 | mp1 | mp2 | mp3) {
                unsigned long long mm;
                #pragma unroll
                for (int q = 0; q < 4; ++q) {
                    mm = (q == 0) ? mp0 : (q == 1) ? mp1 : (q == 2) ? mp2 : mp3;
                    while (mm) {
                        int i = __ffsll(mm) - 1; mm &= mm - 1;
                        float2 wv = wr2i[(size_t)(q * 64 + i) * HH + tid];
                        ce += wv.x; ci += wv.y;
                    }
                }
            }
        }
        ge = 0.98f * ge + ie + (rs.x - ce);
        gi = 0.99f * gi + ii + (rs.y - ci);
        v = v + 0.5f * (0.25f * (0.f - v) + ge * (60.f - v) + gi * (0.f - v));
        float z = (v - 1.f > 0.f) ? 1.f : 0.f;
        v *= (1.f - z);
        spk[((size_t)t * BB + b) * HH + tid] = z;

        unsigned long long nf = __ballot(z == 0.f);
        if (l == 0) mbuf[w] = nf;
        __syncthreads();
        mp0 = mbuf[0]; mp1 = mbuf[1]; mp2 = mbuf[2]; mp3 = mbuf[3];

        if (tid < OO) {
            float corr = 0.f;
            if (mp0 | mp1 | mp2 | mp3) {
                unsigned long long mm;
                mm = mp0; while (mm) { int i = __ffsll(mm) - 1; mm &= mm - 1; corr += woT[(0*64+i)*OO + tid]; }
                mm = mp1; while (mm) { int i = __ffsll(mm) - 1; mm &= mm - 1; corr += woT[(1*64+i)*OO + tid]; }
                mm = mp2; while (mm) { int i = __ffsll(mm) - 1; mm &= mm - 1; corr += woT[(2*64+i)*OO + tid]; }
                mm = mp3; while (mm) { int i = __ffsll(mm) - 1; mm &= mm - 1; corr += woT[(3*64+i)*OO + tid]; }
            }
            vo = vo + 0.01f * (io - vo);
            io = 0.98f * io + (cs - corr);
            volt[((size_t)t * BB + b) * OO + tid] = vo;
        }
    }
}

extern "C" void kernel_launch(void* const* d_in, const int* in_sizes, int n_in,
                              void* d_out, int out_size, void* d_ws, size_t ws_size,
                              hipStream_t stream) {
    (void)in_sizes; (void)n_in; (void)out_size; (void)ws_size;
    const float* x     = (const float*)d_in[0];
    const float* w_in  = (const float*)d_in[1];
    const float* w_rec = (const float*)d_in[2];
    const float* w_out = (const float*)d_in[3];
    float* out = (float*)d_out;

    char* ws = (char*)d_ws;
    float2* wr2i  = (float2*)(ws + WS_WRT);
    float2* rsum  = (float2*)(ws + WS_RSUM);
    float*  woT   = (float*) (ws + WS_WOT);
    float*  csum  = (float*) (ws + WS_CSUM);
    float*  voc   = (float*) (ws + WS_VOC);
    int*    gflag = (int*)   (ws + WS_GFLAG);
    int*    bflag = (int*)   (ws + WS_BFLAG);

    float* volt = out;                                   // [T,B,O]
    float* spk  = out + (size_t)TT * BB * OO;            // [T,B,H]
    float4* spk_t1 = (float4*)(spk + (size_t)BB * HH);   // t>=1 region (16B-aligned)
    const long n4 = (long)(TT - 1) * BB * HH / 4;        // 16,367,616

    hipLaunchKernelGGL(prep_wr2_k,   dim3(HH * HH / 256), dim3(256), 0, stream, w_rec, wr2i);
    hipLaunchKernelGGL(prep_red_k,   dim3(HH + 1),        dim3(64),  0, stream,
                       w_rec, w_out, rsum, woT, csum);
    hipLaunchKernelGGL(drive0_k,     dim3(BB),            dim3(256), 0, stream,
                       x, w_in, spk, bflag);
    hipLaunchKernelGGL(volt_scan_k,  dim3(1),             dim3(64),  0, stream,
                       rsum, csum, voc, gflag);
    hipLaunchKernelGGL(volt_fill_k,  dim3(TT),            dim3(256), 0, stream, voc, volt);
    hipLaunchKernelGGL(spike_fill_k, dim3(63936),         dim3(256), 0, stream, spk_t1, n4);
    hipLaunchKernelGGL(fallback_k,   dim3(BB),            dim3(256), 0, stream,
                       x, w_in, wr2i, rsum, woT, csum, gflag, bflag, out);
}